// Round 12
// baseline (2553.788 us; speedup 1.0000x reference)
//
#include <hip/hip_runtime.h>
#include <math.h>

// ---------------------------------------------------------------------------
// PiTWithCoords: position-attention transformer on fixed grids.
//  * m_dist EXACT in fp32: d_int / 2^S (down S=13, proc S=11, up S=13).
//  * percentile mask == integer threshold on d_int (joint binary searches).
//  * att weights input/batch-independent; down/proc = sparse gather with
//    precomputed normalized weights; h=blk&7 XCD locality.
//  * UP attention separable (Kronecker): O = Ay*(Ax*V), den = Sx*Sy.
//  * All GEMMs split-bf16 MFMA (a=hi+lo, 3x mfma_f32_16x16x32_bf16).
//  * R11: MEGA-KERNEL — the whole 22-dispatch serial chain after k_pre runs
//    as ONE 512-block kernel with hand-rolled device-scope grid barriers.
//    __launch_bounds__(256,2) guarantees 2 blocks/CU -> all 512 co-resident
//    (max phase LDS 40KB; 2x40KB <= 160KB/CU). Barrier = agent-scope
//    atomic count + acquire spin + threadfence (coop-groups pattern).
// ---------------------------------------------------------------------------

#define PI_F 3.14159265358979323846f
#define NBLK 512

typedef __attribute__((ext_vector_type(8))) short short8;
typedef __attribute__((ext_vector_type(4))) float float4v;
typedef __attribute__((ext_vector_type(4))) unsigned short ushort4v;

__device__ __forceinline__ float gelu_f(float x) {
  float u = 0.7978845608028654f * (x + 0.044715f * x * x * x);
  float e = __expf(2.0f * u);
  float t = 1.0f - 2.0f / (e + 1.0f);
  return 0.5f * x * (1.0f + t);
}

__device__ __forceinline__ float head_scale(float r) {
  return tanf(0.25f * PI_F * (1.0f - 1e-7f) * (1.0f + sinf(r)));
}

__device__ __forceinline__ unsigned short f2bf(float f) {
  union { float f; unsigned u; } c; c.f = f;
  unsigned u = c.u + 0x7FFFu + ((c.u >> 16) & 1u);
  return (unsigned short)(u >> 16);
}
__device__ __forceinline__ float bf2f(unsigned short h) {
  union { unsigned u; float f; } c; c.u = ((unsigned)h) << 16;
  return c.f;
}
__device__ __forceinline__ void split_bf(float f, unsigned short& hi,
                                         unsigned short& lo) {
  hi = f2bf(f);
  lo = f2bf(f - bf2f(hi));
}

// Device-scope counting grid barrier. All NBLK blocks co-resident
// (guaranteed by __launch_bounds__(256,2) at grid=512). n = barrier ordinal.
__device__ __forceinline__ void gbar(int* cnt, int n) {
  __syncthreads();
  if (threadIdx.x == 0) {
    __hip_atomic_fetch_add(cnt, 1, __ATOMIC_ACQ_REL, __HIP_MEMORY_SCOPE_AGENT);
    while (__hip_atomic_load(cnt, __ATOMIC_ACQUIRE,
                             __HIP_MEMORY_SCOPE_AGENT) < NBLK * n)
      __builtin_amdgcn_s_sleep(2);
  }
  __syncthreads();
  __threadfence();
}

// ---------------------------------------------------------------------------
// Pre-pass (separate kernel, 37760 blocks): encoder -> bf16 hi/lo,
// weight split, out init, barrier-counter init.
// ---------------------------------------------------------------------------
__global__ __launch_bounds__(256) void k_pre(
    const float* __restrict__ x, const float* __restrict__ en_w,
    const float* __restrict__ en_b, unsigned short* __restrict__ ahi,
    unsigned short* __restrict__ alo, const float* __restrict__ down_w,
    const float* __restrict__ de1_w, const float* __restrict__ up_w,
    const float* __restrict__ pa_w, const float* __restrict__ mlp1_w,
    const float* __restrict__ mlp2_w, const float* __restrict__ res_w,
    unsigned short* __restrict__ whi, unsigned short* __restrict__ wlo,
    float* __restrict__ out, const float* __restrict__ de2_b,
    int* __restrict__ barcnt) {
  int blk = blockIdx.x;
  int tid = threadIdx.x;
  if (blk < 32768) {
    float4 xv = *(const float4*)(x + (size_t)blk * 4);
    float4 wv = *(const float4*)(en_w + (size_t)tid * 4);
    float s = xv.x * wv.x + xv.y * wv.y + xv.z * wv.z + xv.w * wv.w + en_b[tid];
    s = gelu_f(s);
    unsigned short hi, lo;
    split_bf(s, hi, lo);
    ahi[(size_t)blk * 256 + tid] = hi;
    alo[(size_t)blk * 256 + tid] = lo;
  } else if (blk < 37632) {
    int i = (blk - 32768) * 256 + tid;
    float f;
    if (i < 65536) {
      int n = i >> 8, k = i & 255;
      f = down_w[(n >> 5) * 8192 + k * 32 + (n & 31)];
    } else if (i < 131072) {
      f = de1_w[i - 65536];
    } else if (i < 196608) {
      int j = i - 131072;
      int n = j >> 8, k = j & 255;
      f = up_w[(n >> 5) * 8192 + k * 32 + (n & 31)];
    } else if (i < 458752) {
      int j = i - 196608;
      int b2 = j >> 16, r = j & 65535;
      int n = r >> 8, k = r & 255;
      f = pa_w[(size_t)b2 * 65536 + (n >> 5) * 8192 + k * 32 + (n & 31)];
    } else if (i < 720896) {
      f = mlp1_w[i - 458752];
    } else if (i < 983040) {
      f = mlp2_w[i - 720896];
    } else {
      f = res_w[i - 983040];
    }
    unsigned short hi, lo;
    split_bf(f, hi, lo);
    whi[i] = hi;
    wlo[i] = lo;
  } else {
    if (blk == 37632 && tid == 0) *barcnt = 0;
    out[(blk - 37632) * 256 + tid] = de2_b[0];
  }
}

// ---------------------------------------------------------------------------
// Phase: klist (2x2-q-tile union key list + normalized weights; thresholds
// via 4 joint binary searches). smem usage 5316 B.
// ---------------------------------------------------------------------------
template <int KRES, int CXM, int DSHIFT, int J2, int NPT, int TARGET,
          int ITERS, int TMAX>
__device__ void ph_klist(unsigned char* sm, const float* rvec, int* klist2,
                         int* kcnt2, float* wlist2, int tile, int tid) {
  int* sidx = (int*)sm;                          // J2 ints
  int (*sdv)[4] = (int (*)[4])(sm + 1024);       // J2 x 4 ints
  float (*denS)[4] = (float (*)[4])(sm + 5120);  // 8 x 4
  int (*wsum4)[4] = (int (*)[4])(sm + 5248);     // 4 x 4
  int* cntS = (int*)(sm + 5312);
  int tx = tile & 15, ty = tile >> 4;
  int cxA[4], cyA[4];
#pragma unroll
  for (int i = 0; i < 4; ++i) {
    int qx = 2 * tx + (i & 1), qy = 2 * ty + (i >> 1);
    cxA[i] = qx * CXM; cyA[i] = qy * CXM;
  }
  int dc[4][NPT];
#pragma unroll
  for (int j = 0; j < NPT; ++j) {
    int p = tid * NPT + j;
    int kx = p & (KRES - 1), ky = p / KRES;
#pragma unroll
    for (int i = 0; i < 4; ++i) {
      int dx = cxA[i] - kx, dy = cyA[i] - ky;
      dc[i][j] = dx * dx + dy * dy;
    }
  }
  int lo4[4] = {0, 0, 0, 0}, hi4[4] = {TMAX, TMAX, TMAX, TMAX};
  for (int it = 0; it < ITERS; ++it) {
    int mid[4], c[4] = {0, 0, 0, 0};
#pragma unroll
    for (int i = 0; i < 4; ++i) {
      mid[i] = (lo4[i] + hi4[i]) >> 1;
      if (lo4[i] < hi4[i]) {
#pragma unroll
        for (int j = 0; j < NPT; ++j) c[i] += (dc[i][j] <= mid[i]) ? 1 : 0;
      }
    }
#pragma unroll
    for (int i = 0; i < 4; ++i)
#pragma unroll
      for (int off = 32; off > 0; off >>= 1)
        c[i] += __shfl_down(c[i], off, 64);
    if ((tid & 63) == 0) {
#pragma unroll
      for (int i = 0; i < 4; ++i) wsum4[tid >> 6][i] = c[i];
    }
    __syncthreads();
#pragma unroll
    for (int i = 0; i < 4; ++i) {
      if (lo4[i] < hi4[i]) {
        int tot = wsum4[0][i] + wsum4[1][i] + wsum4[2][i] + wsum4[3][i];
        if (tot >= TARGET) hi4[i] = mid[i]; else lo4[i] = mid[i] + 1;
      }
    }
    __syncthreads();
  }
  int T[4];
#pragma unroll
  for (int i = 0; i < 4; ++i) T[i] = lo4[i];
  if (tid == 0) *cntS = 0;
  __syncthreads();
  int x0 = KRES - 1, x1 = 0, y0 = KRES - 1, y1 = 0;
#pragma unroll
  for (int i = 0; i < 4; ++i) {
    int rad = (int)sqrtf((float)T[i]);
    while ((rad + 1) * (rad + 1) <= T[i]) ++rad;
    while (rad > 0 && rad * rad > T[i]) --rad;
    x0 = min(x0, max(0, cxA[i] - rad));
    x1 = max(x1, min(KRES - 1, cxA[i] + rad));
    y0 = min(y0, max(0, cyA[i] - rad));
    y1 = max(y1, min(KRES - 1, cyA[i] + rad));
  }
  int W = x1 - x0 + 1, H = y1 - y0 + 1, tot = W * H;
  for (int p = tid; p < tot; p += 256) {
    int kx = x0 + p % W, ky = y0 + p / W;
    int d[4]; bool keep = false;
#pragma unroll
    for (int i = 0; i < 4; ++i) {
      int dx = cxA[i] - kx, dy = cyA[i] - ky;
      d[i] = dx * dx + dy * dy;
      keep = keep || (d[i] <= T[i]);
    }
    if (keep) {
      int s = atomicAdd(cntS, 1);
      if (s < J2) {
        sidx[s] = ky * KRES + kx;
#pragma unroll
        for (int i = 0; i < 4; ++i) sdv[s][i] = d[i];
      }
    }
  }
  __syncthreads();
  int cnt = min(*cntS, J2);
  int h = tid >> 5, lane = tid & 31;
  float sc = head_scale(rvec[h]) * (1.0f / (float)(1 << DSHIFT));
  float den[4] = {0.f, 0.f, 0.f, 0.f};
  for (int j = lane; j < cnt; j += 32) {
#pragma unroll
    for (int i = 0; i < 4; ++i)
      if (sdv[j][i] <= T[i]) den[i] += __expf(-sc * (float)sdv[j][i]);
  }
#pragma unroll
  for (int i = 0; i < 4; ++i) {
    float d0 = den[i];
#pragma unroll
    for (int off = 16; off > 0; off >>= 1) d0 += __shfl_down(d0, off, 32);
    if (lane == 0) denS[h][i] = d0;
  }
  __syncthreads();
  float inv[4];
#pragma unroll
  for (int i = 0; i < 4; ++i) inv[i] = 1.0f / denS[h][i];
  for (int j = lane; j < cnt; j += 32) {
    float w[4];
#pragma unroll
    for (int i = 0; i < 4; ++i)
      w[i] = (sdv[j][i] <= T[i]) ? __expf(-sc * (float)sdv[j][i]) * inv[i] : 0.f;
    float4v wv = {w[0], w[1], w[2], w[3]};
    *(float4v*)&wlist2[(((size_t)h * 256 + tile) * J2 + j) * 4] = wv;
  }
  if (tid == 0) kcnt2[tile] = cnt;
  if (h == 0)
    for (int j = lane; j < cnt; j += 32) klist2[(size_t)tile * J2 + j] = sidx[j];
}

// ---------------------------------------------------------------------------
// Phase: tiled sparse attention (one (tile,h) pair). smem 21504 B.
// ---------------------------------------------------------------------------
template <int NK, int J2>
__device__ void ph_att3(unsigned char* sm, const float* value,
                        const int* klist2, const int* kcnt2,
                        const float* wlist2, unsigned short* ohi,
                        unsigned short* olo, int tile, int h, int tid) {
  int* kls = (int*)sm;                               // 1024 B
  float4v* wls = (float4v*)(sm + 1024);              // 4096 B
  float4v (*part)[4][64] = (float4v (*)[4][64])(sm + 5120);  // 16384 B
  int g = tid & 63, s = tid >> 6;
  int cnt = kcnt2[tile];
  for (int j = tid; j < cnt; j += 256) {
    kls[j] = klist2[(size_t)tile * J2 + j];
    wls[j] = *(const float4v*)&wlist2[(((size_t)h * 256 + tile) * J2 + j) * 4];
  }
  __syncthreads();
  const float* vb = value + (size_t)h * NK * 256 + g * 4;
  float4v acc[4];
#pragma unroll
  for (int i = 0; i < 4; ++i) acc[i] = (float4v)0.0f;
  for (int j = s; j < cnt; j += 4) {
    int row = kls[j];
    float4v v = *(const float4v*)(vb + (size_t)row * 256);
    float4v w = wls[j];
    acc[0] += w.x * v;
    acc[1] += w.y * v;
    acc[2] += w.z * v;
    acc[3] += w.w * v;
  }
#pragma unroll
  for (int i = 0; i < 4; ++i) part[s][i][g] = acc[i];
  __syncthreads();
  if (tid < 64) {
    int g2 = tid;
    int ttx = tile & 15, tty = tile >> 4;
    int batch = g2 >> 3, v0 = (g2 & 7) * 4;
#pragma unroll
    for (int i = 0; i < 4; ++i) {
      float4v o4 = part[0][i][g2] + part[1][i][g2] + part[2][i][g2] +
                   part[3][i][g2];
      int q = (2 * tty + (i >> 1)) * 32 + 2 * ttx + (i & 1);
      size_t idx = ((size_t)batch * 1024 + q) * 256 + h * 32 + v0;
      ushort4v hv, lv;
#pragma unroll
      for (int c = 0; c < 4; ++c) {
        float oo = gelu_f(o4[c]);
        unsigned short hi, lo;
        split_bf(oo, hi, lo);
        hv[c] = hi; lv[c] = lo;
      }
      *(ushort4v*)(ohi + idx) = hv;
      *(ushort4v*)(olo + idx) = lv;
    }
  }
}

// ---------------------------------------------------------------------------
// Phase: split-bf16 MFMA GEMM, 128x128 tile. smem 40960 B.
// ---------------------------------------------------------------------------
typedef unsigned short (*U40)[40];
template <int OL, bool GEL>
__device__ void ph_mf(unsigned char* sm, const unsigned short* A1hi,
                      const unsigned short* A1lo, const unsigned short* W1hi,
                      const unsigned short* W1lo, const float* bias,
                      float* outf, int NS, int bx, int by, int tid) {
  U40 Ah = (U40)sm;
  U40 Al = (U40)(sm + 10240);
  U40 Bh = (U40)(sm + 20480);
  U40 Bl = (U40)(sm + 30720);
  int m0 = bx * 128, n0 = by * 128;
  int w = tid >> 6, lane = tid & 63;
  int wm = (w >> 1) * 64, wn = (w & 1) * 64;
  int quad = lane >> 4, l16 = lane & 15;
  float4v acc[4][4];
#pragma unroll
  for (int i = 0; i < 4; ++i)
#pragma unroll
    for (int j = 0; j < 4; ++j) acc[i][j] = (float4v)0.0f;
  int srow = tid >> 1, skq = (tid & 1) * 16;
  for (int kk = 0; kk < 256; kk += 32) {
    {
      size_t ga = (size_t)(m0 + srow) * 256 + kk + skq;
      const uint4* pah = (const uint4*)(A1hi + ga);
      const uint4* pal = (const uint4*)(A1lo + ga);
      *(uint4*)&Ah[srow][skq] = pah[0];
      *(uint4*)&Ah[srow][skq + 8] = pah[1];
      *(uint4*)&Al[srow][skq] = pal[0];
      *(uint4*)&Al[srow][skq + 8] = pal[1];
      size_t gb = (size_t)(n0 + srow) * 256 + kk + skq;
      const uint4* pbh = (const uint4*)(W1hi + gb);
      const uint4* pbl = (const uint4*)(W1lo + gb);
      *(uint4*)&Bh[srow][skq] = pbh[0];
      *(uint4*)&Bh[srow][skq + 8] = pbh[1];
      *(uint4*)&Bl[srow][skq] = pbl[0];
      *(uint4*)&Bl[srow][skq + 8] = pbl[1];
    }
    __syncthreads();
    short8 ah[4], al[4], bh[4], bl[4];
#pragma unroll
    for (int s = 0; s < 4; ++s) {
      ah[s] = *(const short8*)&Ah[wm + s * 16 + l16][quad * 8];
      al[s] = *(const short8*)&Al[wm + s * 16 + l16][quad * 8];
      bh[s] = *(const short8*)&Bh[wn + s * 16 + l16][quad * 8];
      bl[s] = *(const short8*)&Bl[wn + s * 16 + l16][quad * 8];
    }
#pragma unroll
    for (int ms = 0; ms < 4; ++ms)
#pragma unroll
      for (int ns = 0; ns < 4; ++ns) {
        acc[ms][ns] = __builtin_amdgcn_mfma_f32_16x16x32_bf16(
            ah[ms], bh[ns], acc[ms][ns], 0, 0, 0);
        acc[ms][ns] = __builtin_amdgcn_mfma_f32_16x16x32_bf16(
            ah[ms], bl[ns], acc[ms][ns], 0, 0, 0);
        acc[ms][ns] = __builtin_amdgcn_mfma_f32_16x16x32_bf16(
            al[ms], bh[ns], acc[ms][ns], 0, 0, 0);
      }
    __syncthreads();
  }
#pragma unroll
  for (int ms = 0; ms < 4; ++ms) {
#pragma unroll
    for (int ns = 0; ns < 4; ++ns) {
      int n = n0 + wn + ns * 16 + l16;
      float bv = bias ? bias[n] : 0.0f;
#pragma unroll
      for (int r = 0; r < 4; ++r) {
        int m = m0 + wm + ms * 16 + quad * 4 + r;
        float c = acc[ms][ns][r] + bv;
        if (GEL) c = gelu_f(c);
        if (OL == 0) {
          outf[(size_t)m * 256 + n] = c;
        } else {
          int N = 1 << NS;
          int bb = m >> NS, rr = m & (N - 1);
          outf[(((size_t)(n >> 5) * N + rr) * 8 + bb) * 32 + (n & 31)] = c;
        }
      }
    }
  }
}

// ---------------------------------------------------------------------------
// Phase: dec fc1+fc2 fused (128x128 MFMA + shfl reduce + atomicAdd).
// ---------------------------------------------------------------------------
__device__ void ph_mf_dec(unsigned char* sm, const unsigned short* A1hi,
                          const unsigned short* A1lo,
                          const unsigned short* W1hi,
                          const unsigned short* W1lo, const float* b1,
                          const float* w2, float* out, int bx, int by,
                          int tid) {
  U40 Ah = (U40)sm;
  U40 Al = (U40)(sm + 10240);
  U40 Bh = (U40)(sm + 20480);
  U40 Bl = (U40)(sm + 30720);
  int m0 = bx * 128, n0 = by * 128;
  int w = tid >> 6, lane = tid & 63;
  int wm = (w >> 1) * 64, wn = (w & 1) * 64;
  int quad = lane >> 4, l16 = lane & 15;
  float4v acc[4][4];
#pragma unroll
  for (int i = 0; i < 4; ++i)
#pragma unroll
    for (int j = 0; j < 4; ++j) acc[i][j] = (float4v)0.0f;
  int srow = tid >> 1, skq = (tid & 1) * 16;
  for (int kk = 0; kk < 256; kk += 32) {
    {
      size_t ga = (size_t)(m0 + srow) * 256 + kk + skq;
      const uint4* pah = (const uint4*)(A1hi + ga);
      const uint4* pal = (const uint4*)(A1lo + ga);
      *(uint4*)&Ah[srow][skq] = pah[0];
      *(uint4*)&Ah[srow][skq + 8] = pah[1];
      *(uint4*)&Al[srow][skq] = pal[0];
      *(uint4*)&Al[srow][skq + 8] = pal[1];
      size_t gb = (size_t)(n0 + srow) * 256 + kk + skq;
      const uint4* pbh = (const uint4*)(W1hi + gb);
      const uint4* pbl = (const uint4*)(W1lo + gb);
      *(uint4*)&Bh[srow][skq] = pbh[0];
      *(uint4*)&Bh[srow][skq + 8] = pbh[1];
      *(uint4*)&Bl[srow][skq] = pbl[0];
      *(uint4*)&Bl[srow][skq + 8] = pbl[1];
    }
    __syncthreads();
    short8 ah[4], al[4], bh[4], bl[4];
#pragma unroll
    for (int s = 0; s < 4; ++s) {
      ah[s] = *(const short8*)&Ah[wm + s * 16 + l16][quad * 8];
      al[s] = *(const short8*)&Al[wm + s * 16 + l16][quad * 8];
      bh[s] = *(const short8*)&Bh[wn + s * 16 + l16][quad * 8];
      bl[s] = *(const short8*)&Bl[wn + s * 16 + l16][quad * 8];
    }
#pragma unroll
    for (int ms = 0; ms < 4; ++ms)
#pragma unroll
      for (int ns = 0; ns < 4; ++ns) {
        acc[ms][ns] = __builtin_amdgcn_mfma_f32_16x16x32_bf16(
            ah[ms], bh[ns], acc[ms][ns], 0, 0, 0);
        acc[ms][ns] = __builtin_amdgcn_mfma_f32_16x16x32_bf16(
            ah[ms], bl[ns], acc[ms][ns], 0, 0, 0);
        acc[ms][ns] = __builtin_amdgcn_mfma_f32_16x16x32_bf16(
            al[ms], bh[ns], acc[ms][ns], 0, 0, 0);
      }
    __syncthreads();
  }
#pragma unroll
  for (int ms = 0; ms < 4; ++ms) {
#pragma unroll
    for (int r = 0; r < 4; ++r) {
      float p = 0.0f;
#pragma unroll
      for (int ns = 0; ns < 4; ++ns) {
        int n = n0 + wn + ns * 16 + l16;
        float c = gelu_f(acc[ms][ns][r] + b1[n]);
        p += c * w2[n];
      }
      p += __shfl_xor(p, 1, 64);
      p += __shfl_xor(p, 2, 64);
      p += __shfl_xor(p, 4, 64);
      p += __shfl_xor(p, 8, 64);
      if (l16 == 0) {
        int m = m0 + wm + ms * 16 + quad * 4 + r;
        atomicAdd(&out[m], p);
      }
    }
  }
}

// ---------------------------------------------------------------------------
// Phase: split-bf16 MFMA GEMM, 64x64 tile. smem 20480 B.
// ---------------------------------------------------------------------------
template <bool DUAL, int OL, bool GEL, bool OHILO>
__device__ void ph_mf2(unsigned char* sm, const unsigned short* A1hi,
                       const unsigned short* A1lo, const unsigned short* W1hi,
                       const unsigned short* W1lo, const unsigned short* A2hi,
                       const unsigned short* A2lo, const unsigned short* W2hi,
                       const unsigned short* W2lo, const float* bias,
                       const float* bias2, float* outf, unsigned short* ohi,
                       unsigned short* olo, int NS, int bx, int by, int tid) {
  U40 Ah = (U40)sm;
  U40 Al = (U40)(sm + 5120);
  U40 Bh = (U40)(sm + 10240);
  U40 Bl = (U40)(sm + 15360);
  int m0 = bx * 64, n0 = by * 64;
  int w = tid >> 6, lane = tid & 63;
  int wm = (w >> 1) * 32, wn = (w & 1) * 32;
  int quad = lane >> 4, l16 = lane & 15;
  float4v acc[2][2];
#pragma unroll
  for (int i = 0; i < 2; ++i)
#pragma unroll
    for (int j = 0; j < 2; ++j) acc[i][j] = (float4v)0.0f;
  int srow = tid >> 2, skq = (tid & 3) * 8;
  const int KT = DUAL ? 512 : 256;
  for (int kk = 0; kk < KT; kk += 32) {
    const unsigned short *pAh, *pAl, *pWh, *pWl;
    int kb;
    if (DUAL && kk >= 256) {
      pAh = A2hi; pAl = A2lo; pWh = W2hi; pWl = W2lo; kb = kk - 256;
    } else {
      pAh = A1hi; pAl = A1lo; pWh = W1hi; pWl = W1lo; kb = kk;
    }
    {
      size_t ga = (size_t)(m0 + srow) * 256 + kb + skq;
      *(uint4*)&Ah[srow][skq] = *(const uint4*)(pAh + ga);
      *(uint4*)&Al[srow][skq] = *(const uint4*)(pAl + ga);
      size_t gb = (size_t)(n0 + srow) * 256 + kb + skq;
      *(uint4*)&Bh[srow][skq] = *(const uint4*)(pWh + gb);
      *(uint4*)&Bl[srow][skq] = *(const uint4*)(pWl + gb);
    }
    __syncthreads();
    short8 ah[2], al[2], bh[2], bl[2];
#pragma unroll
    for (int s = 0; s < 2; ++s) {
      ah[s] = *(const short8*)&Ah[wm + s * 16 + l16][quad * 8];
      al[s] = *(const short8*)&Al[wm + s * 16 + l16][quad * 8];
      bh[s] = *(const short8*)&Bh[wn + s * 16 + l16][quad * 8];
      bl[s] = *(const short8*)&Bl[wn + s * 16 + l16][quad * 8];
    }
#pragma unroll
    for (int ms = 0; ms < 2; ++ms)
#pragma unroll
      for (int ns = 0; ns < 2; ++ns) {
        acc[ms][ns] = __builtin_amdgcn_mfma_f32_16x16x32_bf16(
            ah[ms], bh[ns], acc[ms][ns], 0, 0, 0);
        acc[ms][ns] = __builtin_amdgcn_mfma_f32_16x16x32_bf16(
            ah[ms], bl[ns], acc[ms][ns], 0, 0, 0);
        acc[ms][ns] = __builtin_amdgcn_mfma_f32_16x16x32_bf16(
            al[ms], bh[ns], acc[ms][ns], 0, 0, 0);
      }
    __syncthreads();
  }
#pragma unroll
  for (int ms = 0; ms < 2; ++ms) {
#pragma unroll
    for (int ns = 0; ns < 2; ++ns) {
      int n = n0 + wn + ns * 16 + l16;
      float bv = bias ? bias[n] : 0.0f;
      if (DUAL && bias2) bv += bias2[n];
#pragma unroll
      for (int r = 0; r < 4; ++r) {
        int m = m0 + wm + ms * 16 + quad * 4 + r;
        float c = acc[ms][ns][r] + bv;
        if (GEL) c = gelu_f(c);
        if (OHILO) {
          unsigned short chi, clo;
          split_bf(c, chi, clo);
          ohi[(size_t)m * 256 + n] = chi;
          olo[(size_t)m * 256 + n] = clo;
        } else if (OL == 0) {
          outf[(size_t)m * 256 + n] = c;
        } else {
          int N = 1 << NS;
          int bb = m >> NS, rr = m & (N - 1);
          outf[(((size_t)(n >> 5) * N + rr) * 8 + bb) * 32 + (n & 31)] = c;
        }
      }
    }
  }
}

// ---------------------------------------------------------------------------
// Phase: separable up-attention stage 1. smem 4224 B.
// ---------------------------------------------------------------------------
__device__ void ph_s1(unsigned char* sm, const float* value, const float* rvec,
                      float* T, int ky, int h, int z, int tid) {
  float (*AxL)[33] = (float (*)[33])sm;
  int qx0 = z * 32;
  float sc = head_scale(rvec[h]) * (1.0f / 8192.0f);
  float v[32];
  const float* vb = value + ((size_t)h * 1024 + ky * 32) * 256 + tid;
#pragma unroll
  for (int kx = 0; kx < 32; ++kx) v[kx] = vb[kx * 256];
  if (tid < 32) {
    int qx = qx0 + tid, dxmin = qx & 1;
    for (int kx = 0; kx < 32; ++kx) {
      int dx = qx - 2 * kx;
      AxL[tid][kx] = __expf(-sc * (float)(dx * dx - dxmin));
    }
  }
  __syncthreads();
  for (int qq = 0; qq < 32; ++qq) {
    int qx = qx0 + qq;
    float acc = 0.f;
#pragma unroll
    for (int kx = 0; kx < 32; ++kx) acc += AxL[qq][kx] * v[kx];
    T[(((size_t)h * 64 + qx) * 32 + ky) * 256 + tid] = acc;
  }
}

// ---------------------------------------------------------------------------
// Phase: separable up-attention stage 2 -> bf16 hi/lo. smem 8708 B.
// ---------------------------------------------------------------------------
__device__ void ph_s2(unsigned char* sm, const float* T, const float* rvec,
                      unsigned short* ohi, unsigned short* olo, int qx, int h,
                      int tid) {
  float (*AyL)[33] = (float (*)[33])sm;   // 8448
  float* Sy = (float*)(sm + 8448);        // 256
  float* SxS = (float*)(sm + 8704);       // 4
  float sc = head_scale(rvec[h]) * (1.0f / 8192.0f);
  float t[32];
  const float* tb = T + ((size_t)h * 64 + qx) * 32 * 256 + tid;
#pragma unroll
  for (int ky = 0; ky < 32; ++ky) t[ky] = tb[ky * 256];
  if (tid < 64) {
    int qy = tid, dymin = qy & 1;
    float s = 0.f;
    for (int ky = 0; ky < 32; ++ky) {
      int dy = qy - 2 * ky;
      float e = __expf(-sc * (float)(dy * dy - dymin));
      AyL[qy][ky] = e;
      s += e;
    }
    Sy[qy] = s;
  } else if (tid >= 64 && tid < 96) {
    int kx = tid - 64, dxmin = qx & 1;
    int dx = qx - 2 * kx;
    float e = __expf(-sc * (float)(dx * dx - dxmin));
#pragma unroll
    for (int off = 16; off > 0; off >>= 1) e += __shfl_down(e, off, 32);
    if (kx == 0) *SxS = e;
  }
  __syncthreads();
  float invSx = 1.0f / *SxS;
  int b = tid >> 5, v = tid & 31;
  size_t base = ((size_t)b * 4096 + qx) * 256 + h * 32 + v;
  for (int qy = 0; qy < 64; ++qy) {
    float acc = 0.f;
#pragma unroll
    for (int ky = 0; ky < 32; ++ky) acc += AyL[qy][ky] * t[ky];
    float o = gelu_f(acc * invSx / Sy[qy]);
    unsigned short hi, lo;
    split_bf(o, hi, lo);
    size_t idx = base + (size_t)qy * 64 * 256;
    ohi[idx] = hi;
    olo[idx] = lo;
  }
}

// ---------------------------------------------------------------------------
// THE MEGA-KERNEL: 512 blocks, 22 grid barriers, whole network after k_pre.
// __launch_bounds__(256,2) guarantees 2 blocks/CU -> all 512 co-resident.
// ---------------------------------------------------------------------------
__global__ __launch_bounds__(256, 2) void k_mega(
    const float* down_r, const float* pa_r, int* klD2, int* cntD2,
    float* wlD2, int* klP2, int* cntP2, float* wlP2, unsigned short* Ahi,
    unsigned short* Alo, const unsigned short* Whi, const unsigned short* Wlo,
    float* B, float* Tbuf, unsigned short* hAhi, unsigned short* hAlo,
    unsigned short* hBhi, unsigned short* hBlo, unsigned short* pahi,
    unsigned short* palo, unsigned short* m1hi, unsigned short* m1lo,
    const float* mlp1_b, const float* mlp2_b, const float* res_b,
    const float* up_r, const float* de1_b, const float* de2_w, float* out,
    int* barcnt) {
  __shared__ __align__(16) unsigned char SM[40960];
  int blk = blockIdx.x, tid = threadIdx.x;
  int bn = 0;
  const int WO_DOWN = 0, WO_DE1 = 65536, WO_UP = 131072, WO_PA = 196608,
            WO_MLP1 = 458752, WO_MLP2 = 720896, WO_RES = 983040;

  // P1: key lists (down: blocks [0,256), proc: [256,512))
  if (blk < 256)
    ph_klist<64, 2, 13, 256, 16, 82, 13, 7938>(SM, down_r, klD2, cntD2, wlD2,
                                               blk, tid);
  else
    ph_klist<32, 1, 11, 256, 4, 103, 11, 1922>(SM, pa_r, klP2, cntP2, wlP2,
                                               blk - 256, tid);
  gbar(barcnt, ++bn);
  // P2: down value MFMA -> B [h][4096][bv]
  ph_mf<1, false>(SM, Ahi, Alo, Whi + WO_DOWN, Wlo + WO_DOWN, nullptr, B, 12,
                  blk >> 1, blk & 1, tid);
  gbar(barcnt, ++bn);
  // P3: down tiled sparse attention -> hA (4 virtual (tile,h) per block,
  //     v=j*512+blk keeps h=blk&7 XCD locality)
  for (int j = 0; j < 4; ++j) {
    int v = j * 512 + blk;
    ph_att3<4096, 256>(SM, B, klD2, cntD2, wlD2, hAhi, hAlo, v >> 3, v & 7,
                       tid);
    __syncthreads();
  }
  gbar(barcnt, ++bn);
  // P4..P19: processor loop
  for (int i = 0; i < 4; ++i) {
    const unsigned short* hih = (i & 1) ? hBhi : hAhi;
    const unsigned short* hil = (i & 1) ? hBlo : hAlo;
    unsigned short* hoh = (i & 1) ? hAhi : hBhi;
    unsigned short* hol = (i & 1) ? hAlo : hBlo;
    ph_mf2<false, 1, false, false>(SM, hih, hil, Whi + WO_PA + i * 65536,
                                   Wlo + WO_PA + i * 65536, nullptr, nullptr,
                                   nullptr, nullptr, nullptr, nullptr, B,
                                   nullptr, nullptr, 10, blk >> 2, blk & 3,
                                   tid);
    gbar(barcnt, ++bn);
    for (int j = 0; j < 4; ++j) {
      int v = j * 512 + blk;
      ph_att3<1024, 256>(SM, B, klP2, cntP2, wlP2, pahi, palo, v >> 3, v & 7,
                         tid);
      __syncthreads();
    }
    gbar(barcnt, ++bn);
    ph_mf2<false, 0, true, true>(SM, pahi, palo, Whi + WO_MLP1 + i * 65536,
                                 Wlo + WO_MLP1 + i * 65536, nullptr, nullptr,
                                 nullptr, nullptr, mlp1_b + i * 256, nullptr,
                                 nullptr, m1hi, m1lo, 0, blk >> 2, blk & 3,
                                 tid);
    gbar(barcnt, ++bn);
    ph_mf2<true, 0, true, true>(SM, m1hi, m1lo, Whi + WO_MLP2 + i * 65536,
                                Wlo + WO_MLP2 + i * 65536, hih, hil,
                                Whi + WO_RES + i * 65536,
                                Wlo + WO_RES + i * 65536, mlp2_b + i * 256,
                                res_b + i * 256, nullptr, hoh, hol, 0,
                                blk >> 2, blk & 3, tid);
    gbar(barcnt, ++bn);
  }
  // P20: up value MFMA -> B [h][1024][bv]  (final h is in hA after i=3)
  ph_mf2<false, 1, false, false>(SM, hAhi, hAlo, Whi + WO_UP, Wlo + WO_UP,
                                 nullptr, nullptr, nullptr, nullptr, nullptr,
                                 nullptr, B, nullptr, nullptr, 10, blk >> 2,
                                 blk & 3, tid);
  gbar(barcnt, ++bn);
  // P21: separable up stage 1 (grid (32,8,2) flattened)
  ph_s1(SM, B, up_r, Tbuf, blk & 31, (blk >> 5) & 7, blk >> 8, tid);
  gbar(barcnt, ++bn);
  // P22: separable up stage 2 -> Ahi/Alo (grid (64,8) flattened)
  ph_s2(SM, Tbuf, up_r, Ahi, Alo, blk & 63, blk >> 6, tid);
  gbar(barcnt, ++bn);
  // P23: decoder fc1+fc2 fused (grid (256,2) flattened)
  ph_mf_dec(SM, Ahi, Alo, Whi + WO_DE1, Wlo + WO_DE1, de1_b, de2_w, out,
            blk >> 1, blk & 1, tid);
}

// ---------------------------------------------------------------------------
extern "C" void kernel_launch(void* const* d_in, const int* in_sizes, int n_in,
                              void* d_out, int out_size, void* d_ws,
                              size_t ws_size, hipStream_t stream) {
  const float* x      = (const float*)d_in[0];
  const float* en_w   = (const float*)d_in[1];
  const float* en_b   = (const float*)d_in[2];
  const float* down_r = (const float*)d_in[3];
  const float* down_w = (const float*)d_in[4];
  const float* pa_r   = (const float*)d_in[5];
  const float* pa_w   = (const float*)d_in[6];
  const float* mlp1_w = (const float*)d_in[7];
  const float* mlp1_b = (const float*)d_in[8];
  const float* mlp2_w = (const float*)d_in[9];
  const float* mlp2_b = (const float*)d_in[10];
  const float* res_w  = (const float*)d_in[11];
  const float* res_b  = (const float*)d_in[12];
  const float* up_r   = (const float*)d_in[13];
  const float* up_w   = (const float*)d_in[14];
  const float* de1_w  = (const float*)d_in[15];
  const float* de1_b  = (const float*)d_in[16];
  const float* de2_w  = (const float*)d_in[17];
  const float* de2_b  = (const float*)d_in[18];
  float* out = (float*)d_out;

  constexpr int J2 = 256;
  float* ws = (float*)d_ws;
  // [0, 8388608): enc / up_s2 activations, bf16 hi/lo (32768x256 each)
  unsigned short* Ahi = (unsigned short*)ws;
  unsigned short* Alo = Ahi + 8388608;
  // [8388608, 16777216): B fp32 — down value / proc+up value / T
  float* B = ws + 8388608;
  float* Tbuf = B + 2097152;
  // [16777216, 25165824): 8 activation hi/lo buffers, each 2097152 ushorts
  unsigned short* hAhi = (unsigned short*)(ws + 16777216);
  unsigned short* hAlo = hAhi + 2097152;
  unsigned short* hBhi = hAlo + 2097152;
  unsigned short* hBlo = hBhi + 2097152;
  unsigned short* pahi = hBlo + 2097152;
  unsigned short* palo = pahi + 2097152;
  unsigned short* m1hi = palo + 2097152;
  unsigned short* m1lo = m1hi + 2097152;
  // [25165824, ...): misc — AFTER all activation buffers.
  int* cntD2 = (int*)(ws + 25165824);
  int* cntP2 = cntD2 + 256;
  int* barcnt = cntP2 + 256;
  int* klD2 = barcnt + 64;              // [256*J2]
  int* klP2 = klD2 + 256 * J2;
  float* wlD2 = (float*)(klP2 + 256 * J2);  // 2097152 floats
  float* wlP2 = wlD2 + 2097152;
  unsigned short* Whi = (unsigned short*)(wlP2 + 2097152);  // 1245184 each
  unsigned short* Wlo = Whi + 1245184;

  // 1. pre-pass: encoder + weight split + out/barrier init
  k_pre<<<37760, 256, 0, stream>>>(x, en_w, en_b, Ahi, Alo, down_w, de1_w,
                                   up_w, pa_w, mlp1_w, mlp2_w, res_w, Whi,
                                   Wlo, out, de2_b, barcnt);
  // 2. everything else: one mega-kernel, 512 blocks, 22 grid barriers
  k_mega<<<NBLK, 256, 0, stream>>>(
      down_r, pa_r, klD2, cntD2, wlD2, klP2, cntP2, wlP2, Ahi, Alo, Whi, Wlo,
      B, Tbuf, hAhi, hAlo, hBhi, hBlo, pahi, palo, m1hi, m1lo, mlp1_b, mlp2_b,
      res_b, up_r, de1_b, de2_w, out, barcnt);
}

// Round 13
// 484.894 us; speedup vs baseline: 5.2667x; 5.2667x over previous
//
#include <hip/hip_runtime.h>
#include <math.h>

// ---------------------------------------------------------------------------
// PiTWithCoords: position-attention transformer on fixed grids.
//  * m_dist EXACT in fp32: d_int / 2^S (down S=13, proc S=11, up S=13).
//  * percentile mask == integer threshold on d_int (joint binary searches
//    fused into k_klist_all).
//  * att weights input/batch-independent; down/proc = sparse gather with
//    precomputed normalized weights; h in low block bits (XCD locality).
//  * UP attention separable (Kronecker): O = Ay*(Ax*V), den = Sx*Sy.
//  * All GEMMs split-bf16 MFMA (a=hi+lo, 3x mfma_f32_16x16x32_bf16).
//  * R12 post-mortem: device-scope grid barriers cost ~100us each on MI355X
//    (agent-scope acquire => per-XCD L2 invalidate) — mega-kernel reverted.
//  * R13: medium GEMMs on 32x64 tiles -> 1024 blocks (4/CU, was 2/CU) to
//    cut ramp/tail time; everything else = proven R10 structure.
// ---------------------------------------------------------------------------

#define PI_F 3.14159265358979323846f

typedef __attribute__((ext_vector_type(8))) short short8;
typedef __attribute__((ext_vector_type(4))) float float4v;
typedef __attribute__((ext_vector_type(4))) unsigned short ushort4v;

__device__ __forceinline__ float gelu_f(float x) {
  float u = 0.7978845608028654f * (x + 0.044715f * x * x * x);
  float e = __expf(2.0f * u);
  float t = 1.0f - 2.0f / (e + 1.0f);
  return 0.5f * x * (1.0f + t);
}

__device__ __forceinline__ float head_scale(float r) {
  return tanf(0.25f * PI_F * (1.0f - 1e-7f) * (1.0f + sinf(r)));
}

__device__ __forceinline__ unsigned short f2bf(float f) {
  union { float f; unsigned u; } c; c.f = f;
  unsigned u = c.u + 0x7FFFu + ((c.u >> 16) & 1u);
  return (unsigned short)(u >> 16);
}
__device__ __forceinline__ float bf2f(unsigned short h) {
  union { unsigned u; float f; } c; c.u = ((unsigned)h) << 16;
  return c.f;
}
__device__ __forceinline__ void split_bf(float f, unsigned short& hi,
                                         unsigned short& lo) {
  hi = f2bf(f);
  lo = f2bf(f - bf2f(hi));
}

// ---------------------------------------------------------------------------
// Merged pre-pass: encoder (blocks [0,32768)), weight split ([32768,37632)),
// out init ([37632,37760)).
// ---------------------------------------------------------------------------
__global__ __launch_bounds__(256) void k_pre(
    const float* __restrict__ x, const float* __restrict__ en_w,
    const float* __restrict__ en_b, unsigned short* __restrict__ ahi,
    unsigned short* __restrict__ alo, const float* __restrict__ down_w,
    const float* __restrict__ de1_w, const float* __restrict__ up_w,
    const float* __restrict__ pa_w, const float* __restrict__ mlp1_w,
    const float* __restrict__ mlp2_w, const float* __restrict__ res_w,
    unsigned short* __restrict__ whi, unsigned short* __restrict__ wlo,
    float* __restrict__ out, const float* __restrict__ de2_b) {
  int blk = blockIdx.x;
  int tid = threadIdx.x;
  if (blk < 32768) {
    float4 xv = *(const float4*)(x + (size_t)blk * 4);
    float4 wv = *(const float4*)(en_w + (size_t)tid * 4);
    float s = xv.x * wv.x + xv.y * wv.y + xv.z * wv.z + xv.w * wv.w + en_b[tid];
    s = gelu_f(s);
    unsigned short hi, lo;
    split_bf(s, hi, lo);
    ahi[(size_t)blk * 256 + tid] = hi;
    alo[(size_t)blk * 256 + tid] = lo;
  } else if (blk < 37632) {
    int i = (blk - 32768) * 256 + tid;
    float f;
    if (i < 65536) {
      int n = i >> 8, k = i & 255;
      f = down_w[(n >> 5) * 8192 + k * 32 + (n & 31)];
    } else if (i < 131072) {
      f = de1_w[i - 65536];
    } else if (i < 196608) {
      int j = i - 131072;
      int n = j >> 8, k = j & 255;
      f = up_w[(n >> 5) * 8192 + k * 32 + (n & 31)];
    } else if (i < 458752) {
      int j = i - 196608;
      int b2 = j >> 16, r = j & 65535;
      int n = r >> 8, k = r & 255;
      f = pa_w[(size_t)b2 * 65536 + (n >> 5) * 8192 + k * 32 + (n & 31)];
    } else if (i < 720896) {
      f = mlp1_w[i - 458752];
    } else if (i < 983040) {
      f = mlp2_w[i - 720896];
    } else {
      f = res_w[i - 983040];
    }
    unsigned short hi, lo;
    split_bf(f, hi, lo);
    whi[i] = hi;
    wlo[i] = lo;
  } else {
    out[(blk - 37632) * 256 + tid] = de2_b[0];
  }
}

// ---------------------------------------------------------------------------
// klist body: 2x2-q-tile union key list + per-(h,tile,cell) float4 of
// normalized weights (0 outside each disc). Thresholds = 4 joint binary
// searches over register-cached integer distances.
// ---------------------------------------------------------------------------
template <int KRES, int CXM, int DSHIFT, int J2, int NPT, int TARGET,
          int ITERS, int TMAX>
__device__ __forceinline__ void klist_body(
    const float* __restrict__ rvec, int* __restrict__ klist2,
    int* __restrict__ kcnt2, float* __restrict__ wlist2, int tile, int tid) {
  __shared__ int cntS;
  __shared__ int sidx[J2];
  __shared__ int sdv[J2][4];
  __shared__ float denS[8][4];
  __shared__ int wsum4[4][4];
  int tx = tile & 15, ty = tile >> 4;
  int cxA[4], cyA[4];
#pragma unroll
  for (int i = 0; i < 4; ++i) {
    int qx = 2 * tx + (i & 1), qy = 2 * ty + (i >> 1);
    cxA[i] = qx * CXM; cyA[i] = qy * CXM;
  }
  int dc[4][NPT];
#pragma unroll
  for (int j = 0; j < NPT; ++j) {
    int p = tid * NPT + j;
    int kx = p & (KRES - 1), ky = p / KRES;
#pragma unroll
    for (int i = 0; i < 4; ++i) {
      int dx = cxA[i] - kx, dy = cyA[i] - ky;
      dc[i][j] = dx * dx + dy * dy;
    }
  }
  int lo4[4] = {0, 0, 0, 0}, hi4[4] = {TMAX, TMAX, TMAX, TMAX};
  for (int it = 0; it < ITERS; ++it) {
    int mid[4], c[4] = {0, 0, 0, 0};
#pragma unroll
    for (int i = 0; i < 4; ++i) {
      mid[i] = (lo4[i] + hi4[i]) >> 1;
      if (lo4[i] < hi4[i]) {
#pragma unroll
        for (int j = 0; j < NPT; ++j) c[i] += (dc[i][j] <= mid[i]) ? 1 : 0;
      }
    }
#pragma unroll
    for (int i = 0; i < 4; ++i)
#pragma unroll
      for (int off = 32; off > 0; off >>= 1)
        c[i] += __shfl_down(c[i], off, 64);
    if ((tid & 63) == 0) {
#pragma unroll
      for (int i = 0; i < 4; ++i) wsum4[tid >> 6][i] = c[i];
    }
    __syncthreads();
#pragma unroll
    for (int i = 0; i < 4; ++i) {
      if (lo4[i] < hi4[i]) {
        int tot = wsum4[0][i] + wsum4[1][i] + wsum4[2][i] + wsum4[3][i];
        if (tot >= TARGET) hi4[i] = mid[i]; else lo4[i] = mid[i] + 1;
      }
    }
    __syncthreads();
  }
  int T[4];
#pragma unroll
  for (int i = 0; i < 4; ++i) T[i] = lo4[i];
  if (tid == 0) cntS = 0;
  __syncthreads();
  int x0 = KRES - 1, x1 = 0, y0 = KRES - 1, y1 = 0;
#pragma unroll
  for (int i = 0; i < 4; ++i) {
    int rad = (int)sqrtf((float)T[i]);
    while ((rad + 1) * (rad + 1) <= T[i]) ++rad;
    while (rad > 0 && rad * rad > T[i]) --rad;
    x0 = min(x0, max(0, cxA[i] - rad));
    x1 = max(x1, min(KRES - 1, cxA[i] + rad));
    y0 = min(y0, max(0, cyA[i] - rad));
    y1 = max(y1, min(KRES - 1, cyA[i] + rad));
  }
  int W = x1 - x0 + 1, H = y1 - y0 + 1, tot = W * H;
  for (int p = tid; p < tot; p += 256) {
    int kx = x0 + p % W, ky = y0 + p / W;
    int d[4]; bool keep = false;
#pragma unroll
    for (int i = 0; i < 4; ++i) {
      int dx = cxA[i] - kx, dy = cyA[i] - ky;
      d[i] = dx * dx + dy * dy;
      keep = keep || (d[i] <= T[i]);
    }
    if (keep) {
      int s = atomicAdd(&cntS, 1);
      if (s < J2) {
        sidx[s] = ky * KRES + kx;
#pragma unroll
        for (int i = 0; i < 4; ++i) sdv[s][i] = d[i];
      }
    }
  }
  __syncthreads();
  int cnt = min(cntS, J2);
  int h = tid >> 5, lane = tid & 31;
  float sc = head_scale(rvec[h]) * (1.0f / (float)(1 << DSHIFT));
  float den[4] = {0.f, 0.f, 0.f, 0.f};
  for (int j = lane; j < cnt; j += 32) {
#pragma unroll
    for (int i = 0; i < 4; ++i)
      if (sdv[j][i] <= T[i]) den[i] += __expf(-sc * (float)sdv[j][i]);
  }
#pragma unroll
  for (int i = 0; i < 4; ++i) {
    float d0 = den[i];
#pragma unroll
    for (int off = 16; off > 0; off >>= 1) d0 += __shfl_down(d0, off, 32);
    if (lane == 0) denS[h][i] = d0;
  }
  __syncthreads();
  float inv[4];
#pragma unroll
  for (int i = 0; i < 4; ++i) inv[i] = 1.0f / denS[h][i];
  for (int j = lane; j < cnt; j += 32) {
    float w[4];
#pragma unroll
    for (int i = 0; i < 4; ++i)
      w[i] = (sdv[j][i] <= T[i]) ? __expf(-sc * (float)sdv[j][i]) * inv[i] : 0.f;
    float4v wv = {w[0], w[1], w[2], w[3]};
    *(float4v*)&wlist2[(((size_t)h * 256 + tile) * J2 + j) * 4] = wv;
  }
  if (tid == 0) kcnt2[tile] = cnt;
  if (h == 0)
    for (int j = lane; j < cnt; j += 32) klist2[(size_t)tile * J2 + j] = sidx[j];
}

// Merged: blocks [0,256) = down config, [256,512) = proc config.
__global__ __launch_bounds__(256) void k_klist_all(
    const float* __restrict__ down_r, const float* __restrict__ pa_r,
    int* __restrict__ klD2, int* __restrict__ cntD2, float* __restrict__ wlD2,
    int* __restrict__ klP2, int* __restrict__ cntP2, float* __restrict__ wlP2) {
  int tid = threadIdx.x;
  if (blockIdx.x < 256) {
    klist_body<64, 2, 13, 256, 16, 82, 13, 7938>(down_r, klD2, cntD2, wlD2,
                                                 blockIdx.x, tid);
  } else {
    klist_body<32, 1, 11, 256, 4, 103, 11, 1922>(pa_r, klP2, cntP2, wlP2,
                                                 blockIdx.x - 256, tid);
  }
}

// ---------------------------------------------------------------------------
// Tiled sparse attention: block = (2x2 q-tile, h), h in low bits (XCD).
// ---------------------------------------------------------------------------
template <int NK, int J2>
__global__ __launch_bounds__(256) void k_att3(
    const float* __restrict__ value,   // [h][NK][b*32+v]
    const int* __restrict__ klist2, const int* __restrict__ kcnt2,
    const float* __restrict__ wlist2, unsigned short* __restrict__ ohi,
    unsigned short* __restrict__ olo) {
  __shared__ int kls[J2];
  __shared__ float4v wls[J2];
  __shared__ float4v part[4][4][64];
  int blk = blockIdx.x;
  int tile = blk >> 3, h = blk & 7;
  int tid = threadIdx.x, g = tid & 63, s = tid >> 6;
  int cnt = kcnt2[tile];
  for (int j = tid; j < cnt; j += 256) {
    kls[j] = klist2[(size_t)tile * J2 + j];
    wls[j] = *(const float4v*)&wlist2[(((size_t)h * 256 + tile) * J2 + j) * 4];
  }
  __syncthreads();
  const float* vb = value + (size_t)h * NK * 256 + g * 4;
  float4v acc[4];
#pragma unroll
  for (int i = 0; i < 4; ++i) acc[i] = (float4v)0.0f;
  for (int j = s; j < cnt; j += 4) {
    int row = kls[j];
    float4v v = *(const float4v*)(vb + (size_t)row * 256);
    float4v w = wls[j];
    acc[0] += w.x * v;
    acc[1] += w.y * v;
    acc[2] += w.z * v;
    acc[3] += w.w * v;
  }
#pragma unroll
  for (int i = 0; i < 4; ++i) part[s][i][g] = acc[i];
  __syncthreads();
  if (tid < 64) {
    int g2 = tid;
    int ttx = tile & 15, tty = tile >> 4;
    int batch = g2 >> 3, v0 = (g2 & 7) * 4;
#pragma unroll
    for (int i = 0; i < 4; ++i) {
      float4v o4 = part[0][i][g2] + part[1][i][g2] + part[2][i][g2] +
                   part[3][i][g2];
      int q = (2 * tty + (i >> 1)) * 32 + 2 * ttx + (i & 1);
      size_t idx = ((size_t)batch * 1024 + q) * 256 + h * 32 + v0;
      ushort4v hv, lv;
#pragma unroll
      for (int c = 0; c < 4; ++c) {
        float oo = gelu_f(o4[c]);
        unsigned short hi, lo;
        split_bf(oo, hi, lo);
        hv[c] = hi; lv[c] = lo;
      }
      *(ushort4v*)(ohi + idx) = hv;
      *(ushort4v*)(olo + idx) = lv;
    }
  }
}

// ---------------------------------------------------------------------------
// Split-bf16 MFMA GEMM, 128x128 tile (big GEMMs, M=32768).
// ---------------------------------------------------------------------------
template <bool DUAL, int OL, bool GEL, bool OHILO>
__global__ __launch_bounds__(256) void k_mf(
    const unsigned short* __restrict__ A1hi, const unsigned short* __restrict__ A1lo,
    const unsigned short* __restrict__ W1hi, const unsigned short* __restrict__ W1lo,
    const unsigned short* __restrict__ A2hi, const unsigned short* __restrict__ A2lo,
    const unsigned short* __restrict__ W2hi, const unsigned short* __restrict__ W2lo,
    const float* __restrict__ bias, const float* __restrict__ bias2,
    float* __restrict__ outf, unsigned short* __restrict__ ohi,
    unsigned short* __restrict__ olo, int NS) {
  __shared__ unsigned short Ah[128][40], Al[128][40];
  __shared__ unsigned short Bh[128][40], Bl[128][40];
  int tid = threadIdx.x;
  int m0 = blockIdx.x * 128, n0 = blockIdx.y * 128;
  int w = tid >> 6, lane = tid & 63;
  int wm = (w >> 1) * 64, wn = (w & 1) * 64;
  int quad = lane >> 4, l16 = lane & 15;
  float4v acc[4][4];
#pragma unroll
  for (int i = 0; i < 4; ++i)
#pragma unroll
    for (int j = 0; j < 4; ++j) acc[i][j] = (float4v)0.0f;

  int srow = tid >> 1, skq = (tid & 1) * 16;
  const int KT = DUAL ? 512 : 256;
  for (int kk = 0; kk < KT; kk += 32) {
    const unsigned short *pAh, *pAl, *pWh, *pWl;
    int kb;
    if (DUAL && kk >= 256) {
      pAh = A2hi; pAl = A2lo; pWh = W2hi; pWl = W2lo; kb = kk - 256;
    } else {
      pAh = A1hi; pAl = A1lo; pWh = W1hi; pWl = W1lo; kb = kk;
    }
    {
      size_t ga = (size_t)(m0 + srow) * 256 + kb + skq;
      const uint4* pah = (const uint4*)(pAh + ga);
      const uint4* pal = (const uint4*)(pAl + ga);
      *(uint4*)&Ah[srow][skq] = pah[0];
      *(uint4*)&Ah[srow][skq + 8] = pah[1];
      *(uint4*)&Al[srow][skq] = pal[0];
      *(uint4*)&Al[srow][skq + 8] = pal[1];
      size_t gb = (size_t)(n0 + srow) * 256 + kb + skq;
      const uint4* pbh = (const uint4*)(pWh + gb);
      const uint4* pbl = (const uint4*)(pWl + gb);
      *(uint4*)&Bh[srow][skq] = pbh[0];
      *(uint4*)&Bh[srow][skq + 8] = pbh[1];
      *(uint4*)&Bl[srow][skq] = pbl[0];
      *(uint4*)&Bl[srow][skq + 8] = pbl[1];
    }
    __syncthreads();
    short8 ah[4], al[4], bh[4], bl[4];
#pragma unroll
    for (int s = 0; s < 4; ++s) {
      ah[s] = *(const short8*)&Ah[wm + s * 16 + l16][quad * 8];
      al[s] = *(const short8*)&Al[wm + s * 16 + l16][quad * 8];
      bh[s] = *(const short8*)&Bh[wn + s * 16 + l16][quad * 8];
      bl[s] = *(const short8*)&Bl[wn + s * 16 + l16][quad * 8];
    }
#pragma unroll
    for (int ms = 0; ms < 4; ++ms)
#pragma unroll
      for (int ns = 0; ns < 4; ++ns) {
        acc[ms][ns] = __builtin_amdgcn_mfma_f32_16x16x32_bf16(
            ah[ms], bh[ns], acc[ms][ns], 0, 0, 0);
        acc[ms][ns] = __builtin_amdgcn_mfma_f32_16x16x32_bf16(
            ah[ms], bl[ns], acc[ms][ns], 0, 0, 0);
        acc[ms][ns] = __builtin_amdgcn_mfma_f32_16x16x32_bf16(
            al[ms], bh[ns], acc[ms][ns], 0, 0, 0);
      }
    __syncthreads();
  }
#pragma unroll
  for (int ms = 0; ms < 4; ++ms) {
#pragma unroll
    for (int ns = 0; ns < 4; ++ns) {
      int n = n0 + wn + ns * 16 + l16;
      float bv = bias ? bias[n] : 0.0f;
      if (DUAL && bias2) bv += bias2[n];
#pragma unroll
      for (int r = 0; r < 4; ++r) {
        int m = m0 + wm + ms * 16 + quad * 4 + r;
        float c = acc[ms][ns][r] + bv;
        if (GEL) c = gelu_f(c);
        if (OHILO) {
          unsigned short chi, clo;
          split_bf(c, chi, clo);
          ohi[(size_t)m * 256 + n] = chi;
          olo[(size_t)m * 256 + n] = clo;
        } else if (OL == 0) {
          outf[(size_t)m * 256 + n] = c;
        } else {
          int N = 1 << NS;
          int bb = m >> NS, rr = m & (N - 1);
          outf[(((size_t)(n >> 5) * N + rr) * 8 + bb) * 32 + (n & 31)] = c;
        }
      }
    }
  }
}

// ---------------------------------------------------------------------------
// Decoder fc1+fc2 fused: 128x128 MFMA core; epilogue reduces
// sum_n gelu(fc1+b1)*w2[n] via shfl_xor, atomicAdd into out (pre-init b2).
// ---------------------------------------------------------------------------
__global__ __launch_bounds__(256) void k_mf_dec(
    const unsigned short* __restrict__ A1hi, const unsigned short* __restrict__ A1lo,
    const unsigned short* __restrict__ W1hi, const unsigned short* __restrict__ W1lo,
    const float* __restrict__ b1, const float* __restrict__ w2,
    float* __restrict__ out) {
  __shared__ unsigned short Ah[128][40], Al[128][40];
  __shared__ unsigned short Bh[128][40], Bl[128][40];
  int tid = threadIdx.x;
  int m0 = blockIdx.x * 128, n0 = blockIdx.y * 128;
  int w = tid >> 6, lane = tid & 63;
  int wm = (w >> 1) * 64, wn = (w & 1) * 64;
  int quad = lane >> 4, l16 = lane & 15;
  float4v acc[4][4];
#pragma unroll
  for (int i = 0; i < 4; ++i)
#pragma unroll
    for (int j = 0; j < 4; ++j) acc[i][j] = (float4v)0.0f;
  int srow = tid >> 1, skq = (tid & 1) * 16;
  for (int kk = 0; kk < 256; kk += 32) {
    {
      size_t ga = (size_t)(m0 + srow) * 256 + kk + skq;
      const uint4* pah = (const uint4*)(A1hi + ga);
      const uint4* pal = (const uint4*)(A1lo + ga);
      *(uint4*)&Ah[srow][skq] = pah[0];
      *(uint4*)&Ah[srow][skq + 8] = pah[1];
      *(uint4*)&Al[srow][skq] = pal[0];
      *(uint4*)&Al[srow][skq + 8] = pal[1];
      size_t gb = (size_t)(n0 + srow) * 256 + kk + skq;
      const uint4* pbh = (const uint4*)(W1hi + gb);
      const uint4* pbl = (const uint4*)(W1lo + gb);
      *(uint4*)&Bh[srow][skq] = pbh[0];
      *(uint4*)&Bh[srow][skq + 8] = pbh[1];
      *(uint4*)&Bl[srow][skq] = pbl[0];
      *(uint4*)&Bl[srow][skq + 8] = pbl[1];
    }
    __syncthreads();
    short8 ah[4], al[4], bh[4], bl[4];
#pragma unroll
    for (int s = 0; s < 4; ++s) {
      ah[s] = *(const short8*)&Ah[wm + s * 16 + l16][quad * 8];
      al[s] = *(const short8*)&Al[wm + s * 16 + l16][quad * 8];
      bh[s] = *(const short8*)&Bh[wn + s * 16 + l16][quad * 8];
      bl[s] = *(const short8*)&Bl[wn + s * 16 + l16][quad * 8];
    }
#pragma unroll
    for (int ms = 0; ms < 4; ++ms)
#pragma unroll
      for (int ns = 0; ns < 4; ++ns) {
        acc[ms][ns] = __builtin_amdgcn_mfma_f32_16x16x32_bf16(
            ah[ms], bh[ns], acc[ms][ns], 0, 0, 0);
        acc[ms][ns] = __builtin_amdgcn_mfma_f32_16x16x32_bf16(
            ah[ms], bl[ns], acc[ms][ns], 0, 0, 0);
        acc[ms][ns] = __builtin_amdgcn_mfma_f32_16x16x32_bf16(
            al[ms], bh[ns], acc[ms][ns], 0, 0, 0);
      }
    __syncthreads();
  }
#pragma unroll
  for (int ms = 0; ms < 4; ++ms) {
#pragma unroll
    for (int r = 0; r < 4; ++r) {
      float p = 0.0f;
#pragma unroll
      for (int ns = 0; ns < 4; ++ns) {
        int n = n0 + wn + ns * 16 + l16;
        float c = gelu_f(acc[ms][ns][r] + b1[n]);
        p += c * w2[n];
      }
      p += __shfl_xor(p, 1, 64);
      p += __shfl_xor(p, 2, 64);
      p += __shfl_xor(p, 4, 64);
      p += __shfl_xor(p, 8, 64);
      if (l16 == 0) {
        int m = m0 + wm + ms * 16 + quad * 4 + r;
        atomicAdd(&out[m], p);
      }
    }
  }
}

// ---------------------------------------------------------------------------
// Split-bf16 MFMA GEMM, 32x64 tile (medium GEMMs, M=8192 -> grid (256,4) =
// 1024 blocks = 4/CU; R13 ramp/tail fix). 4 waves = 2x2 of 16x32.
// ---------------------------------------------------------------------------
template <bool DUAL, int OL, bool GEL, bool OHILO>
__global__ __launch_bounds__(256) void k_mf3(
    const unsigned short* __restrict__ A1hi, const unsigned short* __restrict__ A1lo,
    const unsigned short* __restrict__ W1hi, const unsigned short* __restrict__ W1lo,
    const unsigned short* __restrict__ A2hi, const unsigned short* __restrict__ A2lo,
    const unsigned short* __restrict__ W2hi, const unsigned short* __restrict__ W2lo,
    const float* __restrict__ bias, const float* __restrict__ bias2,
    float* __restrict__ outf, unsigned short* __restrict__ ohi,
    unsigned short* __restrict__ olo, int NS) {
  __shared__ unsigned short Ah[32][40], Al[32][40];
  __shared__ unsigned short Bh[64][40], Bl[64][40];
  int tid = threadIdx.x;
  int m0 = blockIdx.x * 32, n0 = blockIdx.y * 64;
  int w = tid >> 6, lane = tid & 63;
  int wm = (w >> 1) * 16, wn = (w & 1) * 32;
  int quad = lane >> 4, l16 = lane & 15;
  float4v acc[2];
  acc[0] = (float4v)0.0f;
  acc[1] = (float4v)0.0f;
  int sra = tid >> 3, ska = (tid & 7) * 4;   // A staging: uint2 (4 ushorts)
  int srb = tid >> 2, skb = (tid & 3) * 8;   // B staging: uint4 (8 ushorts)
  const int KT = DUAL ? 512 : 256;
  for (int kk = 0; kk < KT; kk += 32) {
    const unsigned short *pAh, *pAl, *pWh, *pWl;
    int kb;
    if (DUAL && kk >= 256) {
      pAh = A2hi; pAl = A2lo; pWh = W2hi; pWl = W2lo; kb = kk - 256;
    } else {
      pAh = A1hi; pAl = A1lo; pWh = W1hi; pWl = W1lo; kb = kk;
    }
    {
      size_t ga = (size_t)(m0 + sra) * 256 + kb + ska;
      *(uint2*)&Ah[sra][ska] = *(const uint2*)(pAh + ga);
      *(uint2*)&Al[sra][ska] = *(const uint2*)(pAl + ga);
      size_t gb = (size_t)(n0 + srb) * 256 + kb + skb;
      *(uint4*)&Bh[srb][skb] = *(const uint4*)(pWh + gb);
      *(uint4*)&Bl[srb][skb] = *(const uint4*)(pWl + gb);
    }
    __syncthreads();
    short8 ah = *(const short8*)&Ah[wm + l16][quad * 8];
    short8 al = *(const short8*)&Al[wm + l16][quad * 8];
#pragma unroll
    for (int ns = 0; ns < 2; ++ns) {
      short8 bh = *(const short8*)&Bh[wn + ns * 16 + l16][quad * 8];
      short8 bl = *(const short8*)&Bl[wn + ns * 16 + l16][quad * 8];
      acc[ns] = __builtin_amdgcn_mfma_f32_16x16x32_bf16(ah, bh, acc[ns], 0, 0, 0);
      acc[ns] = __builtin_amdgcn_mfma_f32_16x16x32_bf16(ah, bl, acc[ns], 0, 0, 0);
      acc[ns] = __builtin_amdgcn_mfma_f32_16x16x32_bf16(al, bh, acc[ns], 0, 0, 0);
    }
    __syncthreads();
  }
#pragma unroll
  for (int ns = 0; ns < 2; ++ns) {
    int n = n0 + wn + ns * 16 + l16;
    float bv = bias ? bias[n] : 0.0f;
    if (DUAL && bias2) bv += bias2[n];
#pragma unroll
    for (int r = 0; r < 4; ++r) {
      int m = m0 + wm + quad * 4 + r;
      float c = acc[ns][r] + bv;
      if (GEL) c = gelu_f(c);
      if (OHILO) {
        unsigned short chi, clo;
        split_bf(c, chi, clo);
        ohi[(size_t)m * 256 + n] = chi;
        olo[(size_t)m * 256 + n] = clo;
      } else if (OL == 0) {
        outf[(size_t)m * 256 + n] = c;
      } else {
        int N = 1 << NS;
        int bb = m >> NS, rr = m & (N - 1);
        outf[(((size_t)(n >> 5) * N + rr) * 8 + bb) * 32 + (n & 31)] = c;
      }
    }
  }
}

// ---------------------------------------------------------------------------
// Separable up-attention stage 1 (qx split 2x for occupancy).
// ---------------------------------------------------------------------------
__global__ __launch_bounds__(256) void k_up_s1(
    const float* __restrict__ value,  // [h][1024][bv]
    const float* __restrict__ rvec, float* __restrict__ T) {
  __shared__ float AxL[32][33];
  int ky = blockIdx.x, h = blockIdx.y, qx0 = blockIdx.z * 32;
  int tid = threadIdx.x;
  float sc = head_scale(rvec[h]) * (1.0f / 8192.0f);
  float v[32];
  const float* vb = value + ((size_t)h * 1024 + ky * 32) * 256 + tid;
#pragma unroll
  for (int kx = 0; kx < 32; ++kx) v[kx] = vb[kx * 256];
  if (tid < 32) {
    int qx = qx0 + tid, dxmin = qx & 1;
    for (int kx = 0; kx < 32; ++kx) {
      int dx = qx - 2 * kx;
      AxL[tid][kx] = __expf(-sc * (float)(dx * dx - dxmin));
    }
  }
  __syncthreads();
  for (int qq = 0; qq < 32; ++qq) {
    int qx = qx0 + qq;
    float acc = 0.f;
#pragma unroll
    for (int kx = 0; kx < 32; ++kx) acc += AxL[qq][kx] * v[kx];
    T[(((size_t)h * 64 + qx) * 32 + ky) * 256 + tid] = acc;
  }
}

// ---------------------------------------------------------------------------
// Separable up-attention stage 2 -> bf16 hi/lo (feeds dec-fc1 MFMA).
// ---------------------------------------------------------------------------
__global__ __launch_bounds__(256) void k_up_s2(
    const float* __restrict__ T, const float* __restrict__ rvec,
    unsigned short* __restrict__ ohi, unsigned short* __restrict__ olo) {
  __shared__ float AyL[64][33];
  __shared__ float Sy[64];
  __shared__ float SxS;
  int qx = blockIdx.x, h = blockIdx.y, tid = threadIdx.x;
  float sc = head_scale(rvec[h]) * (1.0f / 8192.0f);
  float t[32];
  const float* tb = T + ((size_t)h * 64 + qx) * 32 * 256 + tid;
#pragma unroll
  for (int ky = 0; ky < 32; ++ky) t[ky] = tb[ky * 256];
  if (tid < 64) {
    int qy = tid, dymin = qy & 1;
    float s = 0.f;
    for (int ky = 0; ky < 32; ++ky) {
      int dy = qy - 2 * ky;
      float e = __expf(-sc * (float)(dy * dy - dymin));
      AyL[qy][ky] = e;
      s += e;
    }
    Sy[qy] = s;
  } else if (tid >= 64 && tid < 96) {
    int kx = tid - 64, dxmin = qx & 1;
    int dx = qx - 2 * kx;
    float e = __expf(-sc * (float)(dx * dx - dxmin));
#pragma unroll
    for (int off = 16; off > 0; off >>= 1) e += __shfl_down(e, off, 32);
    if (kx == 0) SxS = e;
  }
  __syncthreads();
  float invSx = 1.0f / SxS;
  int b = tid >> 5, v = tid & 31;
  size_t base = ((size_t)b * 4096 + qx) * 256 + h * 32 + v;
  for (int qy = 0; qy < 64; ++qy) {
    float acc = 0.f;
#pragma unroll
    for (int ky = 0; ky < 32; ++ky) acc += AyL[qy][ky] * t[ky];
    float o = gelu_f(acc * invSx / Sy[qy]);
    unsigned short hi, lo;
    split_bf(o, hi, lo);
    size_t idx = base + (size_t)qy * 64 * 256;
    ohi[idx] = hi;
    olo[idx] = lo;
  }
}

// ---------------------------------------------------------------------------
extern "C" void kernel_launch(void* const* d_in, const int* in_sizes, int n_in,
                              void* d_out, int out_size, void* d_ws,
                              size_t ws_size, hipStream_t stream) {
  const float* x      = (const float*)d_in[0];
  const float* en_w   = (const float*)d_in[1];
  const float* en_b   = (const float*)d_in[2];
  const float* down_r = (const float*)d_in[3];
  const float* down_w = (const float*)d_in[4];
  const float* pa_r   = (const float*)d_in[5];
  const float* pa_w   = (const float*)d_in[6];
  const float* mlp1_w = (const float*)d_in[7];
  const float* mlp1_b = (const float*)d_in[8];
  const float* mlp2_w = (const float*)d_in[9];
  const float* mlp2_b = (const float*)d_in[10];
  const float* res_w  = (const float*)d_in[11];
  const float* res_b  = (const float*)d_in[12];
  const float* up_r   = (const float*)d_in[13];
  const float* up_w   = (const float*)d_in[14];
  const float* de1_w  = (const float*)d_in[15];
  const float* de1_b  = (const float*)d_in[16];
  const float* de2_w  = (const float*)d_in[17];
  const float* de2_b  = (const float*)d_in[18];
  float* out = (float*)d_out;

  constexpr int J2 = 256;
  float* ws = (float*)d_ws;
  // [0, 8388608): enc / up_s2 activations, bf16 hi/lo (32768x256 each)
  unsigned short* Ahi = (unsigned short*)ws;
  unsigned short* Alo = Ahi + 8388608;
  // [8388608, 16777216): B fp32 — down value / proc+up value / T
  float* B = ws + 8388608;
  float* Tbuf = B + 2097152;
  // [16777216, 25165824): 8 activation hi/lo buffers, each 2097152 ushorts
  unsigned short* hAhi = (unsigned short*)(ws + 16777216);
  unsigned short* hAlo = hAhi + 2097152;
  unsigned short* hBhi = hAlo + 2097152;
  unsigned short* hBlo = hBhi + 2097152;
  unsigned short* pahi = hBlo + 2097152;
  unsigned short* palo = pahi + 2097152;
  unsigned short* m1hi = palo + 2097152;
  unsigned short* m1lo = m1hi + 2097152;
  // [25165824, ...): misc — AFTER all activation buffers.
  int* cntD2 = (int*)(ws + 25165824);
  int* cntP2 = cntD2 + 256;
  int* klD2 = cntP2 + 256;              // [256*J2]
  int* klP2 = klD2 + 256 * J2;
  float* wlD2 = (float*)(klP2 + 256 * J2);  // 2097152 floats
  float* wlP2 = wlD2 + 2097152;
  unsigned short* Whi = (unsigned short*)(wlP2 + 2097152);  // 1245184 each
  unsigned short* Wlo = Whi + 1245184;
  const int WO_DOWN = 0, WO_DE1 = 65536, WO_UP = 131072, WO_PA = 196608,
            WO_MLP1 = 458752, WO_MLP2 = 720896, WO_RES = 983040;

  // 1. merged pre-pass: encoder + weight split + out init
  k_pre<<<37760, 256, 0, stream>>>(x, en_w, en_b, Ahi, Alo, down_w, de1_w,
                                   up_w, pa_w, mlp1_w, mlp2_w, res_w, Whi,
                                   Wlo, out, de2_b);
  // 2. merged tiled key lists (fused thresholds), both configs
  k_klist_all<<<512, 256, 0, stream>>>(down_r, pa_r, klD2, cntD2, wlD2, klP2,
                                       cntP2, wlP2);
  // 3. down: value MFMA -> B [h][4096][bv]; tiled sparse att -> hA (hi/lo)
  k_mf<false, 1, false, false><<<dim3(256, 2), 256, 0, stream>>>(
      Ahi, Alo, Whi + WO_DOWN, Wlo + WO_DOWN, nullptr, nullptr, nullptr,
      nullptr, nullptr, nullptr, B, nullptr, nullptr, 12);
  k_att3<4096, J2><<<2048, 256, 0, stream>>>(B, klD2, cntD2, wlD2, hAhi, hAlo);
  // 4. processor blocks, h ping-pong hA <-> hB (32x64-tile MFMA, 1024 blocks)
  for (int i = 0; i < 4; ++i) {
    const unsigned short* hih = (i & 1) ? hBhi : hAhi;
    const unsigned short* hil = (i & 1) ? hBlo : hAlo;
    unsigned short* hoh = (i & 1) ? hAhi : hBhi;
    unsigned short* hol = (i & 1) ? hAlo : hBlo;
    k_mf3<false, 1, false, false><<<dim3(256, 4), 256, 0, stream>>>(
        hih, hil, Whi + WO_PA + i * 65536, Wlo + WO_PA + i * 65536, nullptr,
        nullptr, nullptr, nullptr, nullptr, nullptr, B, nullptr, nullptr, 10);
    k_att3<1024, J2><<<2048, 256, 0, stream>>>(B, klP2, cntP2, wlP2, pahi,
                                               palo);
    k_mf3<false, 0, true, true><<<dim3(256, 4), 256, 0, stream>>>(
        pahi, palo, Whi + WO_MLP1 + i * 65536, Wlo + WO_MLP1 + i * 65536,
        nullptr, nullptr, nullptr, nullptr, mlp1_b + i * 256, nullptr, nullptr,
        m1hi, m1lo, 0);
    k_mf3<true, 0, true, true><<<dim3(256, 4), 256, 0, stream>>>(
        m1hi, m1lo, Whi + WO_MLP2 + i * 65536, Wlo + WO_MLP2 + i * 65536, hih,
        hil, Whi + WO_RES + i * 65536, Wlo + WO_RES + i * 65536,
        mlp2_b + i * 256, res_b + i * 256, nullptr, hoh, hol, 0);
  }
  // 5. up: value MFMA -> B [h][1024][bv]; separable attention
  k_mf3<false, 1, false, false><<<dim3(256, 4), 256, 0, stream>>>(
      hAhi, hAlo, Whi + WO_UP, Wlo + WO_UP, nullptr, nullptr, nullptr, nullptr,
      nullptr, nullptr, B, nullptr, nullptr, 10);
  k_up_s1<<<dim3(32, 8, 2), 256, 0, stream>>>(B, up_r, Tbuf);
  k_up_s2<<<dim3(64, 8), 256, 0, stream>>>(Tbuf, up_r, Ahi, Alo);
  // 6. decoder: fc1+fc2 fused MFMA (out pre-initialized by k_pre)
  k_mf_dec<<<dim3(256, 2), 256, 0, stream>>>(Ahi, Alo, Whi + WO_DE1,
                                             Wlo + WO_DE1, de1_b, de2_w, out);
}